// Round 4
// baseline (286.002 us; speedup 1.0000x reference)
//
#include <hip/hip_runtime.h>

namespace {
constexpr int D       = 128;
constexpr int K       = 1024;
constexpr int M_TOTAL = 65536;   // 16 * 4096
constexpr int BM      = 64;      // rows per block
constexpr int BK      = 64;      // codes per tile
constexpr int NKT     = K / BK;  // 16 code tiles
}

// ---------------- prep: Cn[k] = numpy-pairwise fp32 sum of cb[k,d]^2 ----------------
// numpy pairwise_sum base case (n=128 <= PW_BLOCKSIZE): 8 accumulators over
// separately-rounded squares, combined ((r0+r1)+(r2+r3))+((r4+r5)+(r6+r7)).
__global__ void vq_prep(const float* __restrict__ cb, float* __restrict__ Cn) {
  int k = blockIdx.x * 256 + threadIdx.x;
  if (k >= K) return;
  const float* c = cb + (size_t)k * D;
  float r8[8];
#pragma unroll
  for (int j = 0; j < 8; ++j) r8[j] = __fmul_rn(c[j], c[j]);
  for (int i = 8; i < D; i += 8) {
#pragma unroll
    for (int j = 0; j < 8; ++j)
      r8[j] = __fadd_rn(r8[j], __fmul_rn(c[i + j], c[i + j]));
  }
  Cn[k] = __fadd_rn(__fadd_rn(__fadd_rn(r8[0], r8[1]), __fadd_rn(r8[2], r8[3])),
                    __fadd_rn(__fadd_rn(r8[4], r8[5]), __fadd_rn(r8[6], r8[7])));
}

// ---------------- main: bit-replication of numpy fp32 expanded-distance argmin ----------------
// dist[m,k] = fl( fl( A[m] - fl(2*B[m,k]) ) + C[k] ), with
//   A = numpy-pairwise row norm, C = numpy-pairwise code norm,
//   B = sequential fp32 FMA dot over d (OpenBLAS sgemm microkernel order).
// argmin: strict <, lowest index on fp32 ties (np.argmin first occurrence).
__global__ __launch_bounds__(256) void vq_main(
    const float* __restrict__ z, const float* __restrict__ cb,
    const float* __restrict__ Cn,
    float* __restrict__ out_zq, float* __restrict__ out_q,
    float* __restrict__ out_c, float* __restrict__ out_i) {
  __shared__ float Zt[BM * D];   // 32 KB, XOR-swizzled (validated rounds 2-3)
  __shared__ float Ct[BK * D];   // 32 KB, XOR-swizzled
  __shared__ float Arow[BM];
  __shared__ int   idxArr[BM];

  const int t  = threadIdx.x;
  const int ty = t >> 4;    // 0..15 row groups
  const int tx = t & 15;    // 0..15 code groups
  const int baseRow = blockIdx.x * BM;

  // stage Z tile (swizzled)
  for (int s = t; s < BM * (D / 4); s += 256) {
    int r = s >> 5, d4 = s & 31;
    float4 v = reinterpret_cast<const float4*>(z)[(size_t)(baseRow + r) * (D / 4) + d4];
    int col = d4 ^ (r & 7);
    *reinterpret_cast<float4*>(&Zt[r * D + col * 4]) = v;
  }
  __syncthreads();

  // A[m]: numpy-pairwise fp32 row norms (one thread per row; exact 8-acc recipe)
  if (t < BM) {
    const int rs = t & 7;
    float r8[8];
#pragma unroll
    for (int j = 0; j < 8; ++j) {
      float v = Zt[t * D + (((j >> 2) ^ rs) << 2) + (j & 3)];
      r8[j] = __fmul_rn(v, v);
    }
    for (int i = 8; i < D; i += 8) {
#pragma unroll
      for (int j = 0; j < 8; ++j) {
        int d = i + j;
        float v = Zt[t * D + (((d >> 2) ^ rs) << 2) + (d & 3)];
        r8[j] = __fadd_rn(r8[j], __fmul_rn(v, v));
      }
    }
    Arow[t] = __fadd_rn(__fadd_rn(__fadd_rn(r8[0], r8[1]), __fadd_rn(r8[2], r8[3])),
                        __fadd_rn(__fadd_rn(r8[4], r8[5]), __fadd_rn(r8[6], r8[7])));
  }

  float s1[4]; int i1[4];
#pragma unroll
  for (int i = 0; i < 4; ++i) { s1[i] = 3.402823466e+38f; i1[i] = 0; }

  const int zsw = ty & 7;
  const int csw = tx & 7;

  for (int kt = 0; kt < NKT; ++kt) {
    __syncthreads();
    // stage C tile (swizzled)
    for (int s = t; s < BK * (D / 4); s += 256) {
      int r = s >> 5, d4 = s & 31;
      float4 v = reinterpret_cast<const float4*>(cb)[(size_t)(kt * BK + r) * (D / 4) + d4];
      int col = d4 ^ (r & 7);
      *reinterpret_cast<float4*>(&Ct[r * D + col * 4]) = v;
    }
    __syncthreads();

    // B: one scalar fp32 accumulator per (row,code), sequential FMA d = 0..127
    float acc[4][4];
#pragma unroll
    for (int i = 0; i < 4; ++i)
#pragma unroll
      for (int j = 0; j < 4; ++j) acc[i][j] = 0.f;

    for (int d4 = 0; d4 < 32; ++d4) {   // ascending d4 -> ascending d
      float4 za[4], cv[4];
      int zc = (d4 ^ zsw) * 4;
      int cc = (d4 ^ csw) * 4;
#pragma unroll
      for (int i = 0; i < 4; ++i)
        za[i] = *reinterpret_cast<const float4*>(&Zt[(ty + 16 * i) * D + zc]);
#pragma unroll
      for (int j = 0; j < 4; ++j)
        cv[j] = *reinterpret_cast<const float4*>(&Ct[(tx + 16 * j) * D + cc]);
      // elements x,y,z,w are d = 4*d4+0..3: keep ascending-d chain per accumulator
#pragma unroll
      for (int i = 0; i < 4; ++i)
#pragma unroll
        for (int j = 0; j < 4; ++j) {
          acc[i][j] = fmaf(za[i].x, cv[j].x, acc[i][j]);
          acc[i][j] = fmaf(za[i].y, cv[j].y, acc[i][j]);
          acc[i][j] = fmaf(za[i].z, cv[j].z, acc[i][j]);
          acc[i][j] = fmaf(za[i].w, cv[j].w, acc[i][j]);
        }
    }

    float ch[4]; int kg[4];
#pragma unroll
    for (int j = 0; j < 4; ++j) {
      kg[j] = kt * BK + tx + 16 * j;   // j ascending -> k ascending (per lane)
      ch[j] = Cn[kg[j]];
    }
#pragma unroll
    for (int i = 0; i < 4; ++i) {
      float a = Arow[ty + 16 * i];     // wave-uniform within tx group: broadcast
#pragma unroll
      for (int j = 0; j < 4; ++j) {
        // dist = fl( fl(A - fl(2*B)) + C )  -- contraction-proof intrinsics
        float dist = __fadd_rn(__fsub_rn(a, __fmul_rn(2.0f, acc[i][j])), ch[j]);
        if (dist < s1[i]) { s1[i] = dist; i1[i] = kg[j]; }  // strict <: first index
      }
    }
  }

  // cross-lane min-reduce over the 16 tx lanes; fp32-tie -> lower index
#pragma unroll
  for (int m = 1; m < 16; m <<= 1) {
#pragma unroll
    for (int i = 0; i < 4; ++i) {
      float os = __shfl_xor(s1[i], m, 64);
      int   oi = __shfl_xor(i1[i], m, 64);
      if (os < s1[i] || (os == s1[i] && oi < i1[i])) { s1[i] = os; i1[i] = oi; }
    }
  }

  if (tx == 0) {
#pragma unroll
    for (int i = 0; i < 4; ++i) idxArr[ty + 16 * i] = i1[i];
  }
  __syncthreads();

  // epilogue: gather z_q, STE, losses, index (4 threads per row)
  {
    int r = t >> 2, q = t & 3;
    int idx = idxArr[r];
    size_t m = (size_t)baseRow + r;
    const float4* cq = reinterpret_cast<const float4*>(cb + (size_t)idx * D);
    const float4* zr = reinterpret_cast<const float4*>(z + m * D);
    float4*       o4 = reinterpret_cast<float4*>(out_zq + m * D);
    float sum = 0.f;
#pragma unroll
    for (int e = 0; e < 8; ++e) {
      int d4 = q * 8 + e;
      float4 cv = cq[d4];
      float4 zv = zr[d4];
      float dx = cv.x - zv.x, dy = cv.y - zv.y, dz = cv.z - zv.z, dw = cv.w - zv.w;
      float4 st;
      st.x = zv.x + dx; st.y = zv.y + dy; st.z = zv.z + dz; st.w = zv.w + dw;
      o4[d4] = st;
      sum = fmaf(dx, dx, sum); sum = fmaf(dy, dy, sum);
      sum = fmaf(dz, dz, sum); sum = fmaf(dw, dw, sum);
    }
    sum += __shfl_xor(sum, 1, 64);
    sum += __shfl_xor(sum, 2, 64);
    if (q == 0) {
      float lv = sum * 0.0078125f;   // /128
      out_q[m] = lv;
      out_c[m] = lv;
      out_i[m] = (float)idx;
    }
  }
}

extern "C" void kernel_launch(void* const* d_in, const int* in_sizes, int n_in,
                              void* d_out, int out_size, void* d_ws, size_t ws_size,
                              hipStream_t stream) {
  const float* z  = (const float*)d_in[0];   // [16,4096,128] fp32
  const float* cb = (const float*)d_in[1];   // [1024,128] fp32

  float* out0 = (float*)d_out;               // z_q_ste  [M,128]
  float* out1 = out0 + (size_t)M_TOTAL * D;  // quant_loss [M]
  float* out2 = out1 + M_TOTAL;              // commit_loss [M]
  float* out3 = out2 + M_TOTAL;              // indices (as float) [M]

  float* Cn = (float*)d_ws;                  // |c_k|^2 numpy-pairwise [1024] (4 KB)

  vq_prep<<<(K + 255) / 256, 256, 0, stream>>>(cb, Cn);
  vq_main<<<M_TOTAL / BM, 256, 0, stream>>>(z, cb, Cn, out0, out1, out2, out3);
}